// Round 10
// baseline (252.357 us; speedup 1.0000x reference)
//
#include <hip/hip_runtime.h>
#include <math.h>

#define N_NODES 100000
#define N_EDGES 1600000
#define F_IN 256
#define HIDDEN 64
#define NEG_SLOPE 0.2f

#define BSHIFT 7               // bucket = dst>>7 (128 nodes/bucket)
#define BMASK 127
#define W_BUCKETS 782          // ceil(100000/128)
#define B_SC 512               // hist/scatter blocks (64*8 for scanb)
#define CHUNK 3125             // 512*3125 = 1600000 exactly
#define CAP 2560               // fixed slots per bucket (mean 2045, +11 sigma)

// ---- K0: fold att_src/att_dst/fc_w through lin_w ----
__global__ __launch_bounds__(256) void prep_kernel(
        const float* __restrict__ lin_w, const float* __restrict__ att_src,
        const float* __restrict__ att_dst, const float* __restrict__ fc_w,
        const float* __restrict__ bias, const float* __restrict__ fc_b,
        float* __restrict__ w_all, float* __restrict__ c0) {
    __shared__ float red[256];
    int h = blockIdx.x;   // 0..3
    int f = threadIdx.x;  // 0..255
    float a0 = 0.f, a1 = 0.f, a2 = 0.f;
    for (int c = 0; c < HIDDEN; ++c) {
        float lw = lin_w[(size_t)(h * HIDDEN + c) * F_IN + f];
        a0 += att_src[h * HIDDEN + c] * lw;
        a1 += att_dst[h * HIDDEN + c] * lw;
        a2 += fc_w[h * HIDDEN + c] * lw;
    }
    w_all[(0 + h) * F_IN + f] = a0;
    w_all[(4 + h) * F_IN + f] = a1;
    w_all[(8 + h) * F_IN + f] = a2;
    if (h == 0) {
        red[f] = bias[f] * fc_w[f];
        __syncthreads();
        for (int s = 128; s; s >>= 1) {
            if (f < s) red[f] += red[f + s];
            __syncthreads();
        }
        if (f == 0) c0[0] = red[0] + fc_b[0];
    }
}

// ---- K1: per-node 256x12 matvec; w_all in LDS; 2 nodes per 16-lane group ----
// (the ONLY change vs the R8 241us build: 12 ds_read_b128 per k-step shared
// across 2 x rows -> halves LDS issue; VGPR ~96, no occupancy cliff)
__global__ __launch_bounds__(256) void node_kernel(
        const float* __restrict__ x, const float* __restrict__ w_all,
        float* __restrict__ srcfeat, float* __restrict__ dstfeat) {
    __shared__ float4 lw[768];  // 12 rows x 64 float4 = 12 KB
    int t = threadIdx.x;
    {
        const float4* wr = (const float4*)w_all;
        lw[t] = wr[t];
        lw[t + 256] = wr[t + 256];
        lw[t + 512] = wr[t + 512];
    }
    __syncthreads();
    int tid  = blockIdx.x * 256 + t;
    int wave = tid >> 6;
    int lane = t & 63;
    int sub  = lane >> 4;
    int l16  = lane & 15;
    int n0 = wave * 8 + sub * 2;   // 8 nodes/wave, 2 per 16-lane group
    if (n0 >= N_NODES) return;
    bool has1 = (n0 + 1 < N_NODES);
    const float4* x0 = (const float4*)x + (size_t)n0 * 64;
    float p0[12], p1[12];
#pragma unroll
    for (int r = 0; r < 12; ++r) { p0[r] = 0.f; p1[r] = 0.f; }
#pragma unroll
    for (int k = 0; k < 4; ++k) {
        float4 xv0 = x0[l16 + 16 * k];
        float4 xv1 = has1 ? x0[64 + l16 + 16 * k] : make_float4(0.f, 0.f, 0.f, 0.f);
#pragma unroll
        for (int r = 0; r < 12; ++r) {
            float4 wv = lw[r * 64 + l16 + 16 * k];
            p0[r] += xv0.x * wv.x + xv0.y * wv.y + xv0.z * wv.z + xv0.w * wv.w;
            p1[r] += xv1.x * wv.x + xv1.y * wv.y + xv1.z * wv.z + xv1.w * wv.w;
        }
    }
#pragma unroll
    for (int r = 0; r < 12; ++r) {
        float v = p0[r];
        v += __shfl_xor(v, 1); v += __shfl_xor(v, 2);
        v += __shfl_xor(v, 4); v += __shfl_xor(v, 8);
        p0[r] = v;
        float u = p1[r];
        u += __shfl_xor(u, 1); u += __shfl_xor(u, 2);
        u += __shfl_xor(u, 4); u += __shfl_xor(u, 8);
        p1[r] = u;
    }
    if (l16 == 0) {
        float4* sf = (float4*)(srcfeat + (size_t)n0 * 8);
        sf[0] = make_float4(p0[0], p0[1], p0[2], p0[3]);
        sf[1] = make_float4(p0[8], p0[9], p0[10], p0[11]);
        *(float4*)(dstfeat + (size_t)n0 * 4) = make_float4(p0[4], p0[5], p0[6], p0[7]);
        if (has1) {
            float4* sf1 = (float4*)(srcfeat + (size_t)(n0 + 1) * 8);
            sf1[0] = make_float4(p1[0], p1[1], p1[2], p1[3]);
            sf1[1] = make_float4(p1[8], p1[9], p1[10], p1[11]);
            *(float4*)(dstfeat + (size_t)(n0 + 1) * 4) =
                make_float4(p1[4], p1[5], p1[6], p1[7]);
        }
    }
}

// =================== counting sort, static bucket regions ===================
// hist layout: hist[b * W_BUCKETS + k] (contiguous per block).

__global__ __launch_bounds__(256) void hist2_kernel(
        const int* __restrict__ ei, int* __restrict__ hist) {
    __shared__ int lcnt[W_BUCKETS];
    int t = threadIdx.x, b = blockIdx.x;
    for (int i = t; i < W_BUCKETS; i += 256) lcnt[i] = 0;
    __syncthreads();
    int base = b * CHUNK;
    int end = base + CHUNK; if (end > N_EDGES) end = N_EDGES;
    for (int e = base + t; e < end; e += 256)
        atomicAdd(&lcnt[ei[N_EDGES + e] >> BSHIFT], 1);
    __syncthreads();
    int* hb = hist + (size_t)b * W_BUCKETS;
    for (int i = t; i < W_BUCKETS; i += 256) hb[i] = lcnt[i];
}

// One wave per bucket: exclusive scan of the 512 per-block counts (8/lane),
// rebased to the bucket's static region k*CAP. Writes bucket total to bcnt.
__global__ __launch_bounds__(256) void scanb_kernel(
        int* __restrict__ hist, int* __restrict__ bcnt, int* __restrict__ ocnt) {
    if (blockIdx.x == 0 && threadIdx.x == 0) *ocnt = 0;
    int wv = (blockIdx.x * 256 + threadIdx.x) >> 6;  // bucket id
    int lane = threadIdx.x & 63;
    if (wv >= W_BUCKETS) return;
    int base = lane * 8;
    int v[8];
#pragma unroll
    for (int j = 0; j < 8; ++j)
        v[j] = hist[(size_t)(base + j) * W_BUCKETS + wv];
    int s[8];
    s[0] = v[0];
#pragma unroll
    for (int j = 1; j < 8; ++j) s[j] = s[j - 1] + v[j];
    int tot = s[7];
    int incl = tot;
#pragma unroll
    for (int off = 1; off < 64; off <<= 1) {
        int tmp = __shfl_up(incl, off);
        if (lane >= off) incl += tmp;
    }
    int excl = incl - tot;
    int b0 = wv * CAP;
#pragma unroll
    for (int j = 0; j < 8; ++j) {
        int pref = (j == 0) ? 0 : s[j - 1];
        hist[(size_t)(base + j) * W_BUCKETS + wv] = b0 + excl + pref;
    }
    if (lane == 63) bcnt[wv] = incl;
}

// place edges into static bucket regions: sorted[pos] = src | (dst&127)<<17
__global__ __launch_bounds__(256) void scatter2_kernel(
        const int* __restrict__ ei, const int* __restrict__ goff,
        int* __restrict__ sorted, int* __restrict__ ocnt,
        int2* __restrict__ obuf) {
    __shared__ int lbase[W_BUCKETS];
    int t = threadIdx.x, b = blockIdx.x;
    const int* gb = goff + (size_t)b * W_BUCKETS;
    for (int i = t; i < W_BUCKETS; i += 256) lbase[i] = gb[i];
    __syncthreads();
    int base = b * CHUNK;
    int end = base + CHUNK; if (end > N_EDGES) end = N_EDGES;
    for (int e = base + t; e < end; e += 256) {
        int s = ei[e];
        int d = ei[N_EDGES + e];
        int k = d >> BSHIFT;
        int pos = atomicAdd(&lbase[k], 1);
        if (pos < (k + 1) * CAP) {
            sorted[pos] = s | ((d & BMASK) << 17);
        } else {
            int oi = atomicAdd(ocnt, 1);
            obuf[oi] = make_int2(s, d);
        }
    }
}

// ---- agg4: per-bucket in-LDS fine sort + atomic-free per-node aggregation ----
// (exact R8 version — known 241 us config)
__global__ __launch_bounds__(256) void agg4_kernel(
        const int* __restrict__ sorted, const int* __restrict__ bcnt,
        const float* __restrict__ srcfeat, const float* __restrict__ dstfeat,
        const float* __restrict__ c0, float* __restrict__ out,
        const int* __restrict__ ocnt, const int2* __restrict__ obuf) {
    __shared__ int eds[CAP];
    __shared__ int srt[CAP];
    __shared__ int cnt[128];   // hist, then cursor
    __shared__ int bnd[129];   // exclusive bounds
    __shared__ int s_oc;
    int t = threadIdx.x, k = blockIdx.x;
    if (t == 0) s_oc = *ocnt;
    int begin = k * CAP;
    int len = bcnt[k];
    int lcap = len < CAP ? len : CAP;
    if (t < 128) cnt[t] = 0;
    __syncthreads();
    for (int i = t; i < lcap; i += 256) {
        int p = sorted[begin + i];
        eds[i] = p;
        atomicAdd(&cnt[p >> 17], 1);
    }
    __syncthreads();
    if (t < 128) bnd[t + 1] = cnt[t];
    __syncthreads();
    for (int off = 1; off < 128; off <<= 1) {
        int v = 0;
        if (t < 128 && t >= off) v = bnd[t + 1 - off];
        __syncthreads();
        if (t < 128) bnd[t + 1] += v;
        __syncthreads();
    }
    if (t == 0) bnd[0] = 0;
    if (t < 128) cnt[t] = (t == 0) ? 0 : bnd[t];
    __syncthreads();
    for (int i = t; i < lcap; i += 256) {
        int p = eds[i];
        int pos = atomicAdd(&cnt[p >> 17], 1);
        srt[pos] = p & 0x1FFFF;
    }
    __syncthreads();
    if (t < 128) {
        int n0 = k * 128 + t;
        if (n0 < N_NODES) {
            float4 ad = *(const float4*)(dstfeat + (size_t)n0 * 4);
            float de0 = 0.f, de1 = 0.f, de2 = 0.f, de3 = 0.f;
            float nu0 = 0.f, nu1 = 0.f, nu2 = 0.f, nu3 = 0.f;
            int b0 = bnd[t], e0 = bnd[t + 1];
            for (int i = b0; i < e0; ++i) {
                int s = srt[i];
                const float4* sp = (const float4*)(srcfeat + (size_t)s * 8);
                float4 as = sp[0];
                float4 g  = sp[1];
                float s0 = as.x + ad.x, s1 = as.y + ad.y;
                float s2 = as.z + ad.z, s3 = as.w + ad.w;
                float x0 = __expf(s0 > 0.f ? s0 : NEG_SLOPE * s0);
                float x1 = __expf(s1 > 0.f ? s1 : NEG_SLOPE * s1);
                float x2 = __expf(s2 > 0.f ? s2 : NEG_SLOPE * s2);
                float x3 = __expf(s3 > 0.f ? s3 : NEG_SLOPE * s3);
                de0 += x0; de1 += x1; de2 += x2; de3 += x3;
                nu0 += x0 * g.x; nu1 += x1 * g.y; nu2 += x2 * g.z; nu3 += x3 * g.w;
            }
            // overflow edges (empty in practice)
            for (int i = 0; i < s_oc; ++i) {
                int2 e = obuf[i];
                if ((e.y >> BSHIFT) == k && (e.y & BMASK) == t) {
                    const float4* sp = (const float4*)(srcfeat + (size_t)e.x * 8);
                    float4 as = sp[0];
                    float4 g  = sp[1];
                    float s0 = as.x + ad.x, s1 = as.y + ad.y;
                    float s2 = as.z + ad.z, s3 = as.w + ad.w;
                    float x0 = __expf(s0 > 0.f ? s0 : NEG_SLOPE * s0);
                    float x1 = __expf(s1 > 0.f ? s1 : NEG_SLOPE * s1);
                    float x2 = __expf(s2 > 0.f ? s2 : NEG_SLOPE * s2);
                    float x3 = __expf(s3 > 0.f ? s3 : NEG_SLOPE * s3);
                    de0 += x0; de1 += x1; de2 += x2; de3 += x3;
                    nu0 += x0 * g.x; nu1 += x1 * g.y; nu2 += x2 * g.z; nu3 += x3 * g.w;
                }
            }
            float y = c0[0]
                    + nu0 / (de0 + 1e-16f)
                    + nu1 / (de1 + 1e-16f)
                    + nu2 / (de2 + 1e-16f)
                    + nu3 / (de3 + 1e-16f);
            out[n0] = y;
        }
    }
}

// =================== fallback atomic path (tiny ws) ===================

__global__ __launch_bounds__(256) void init_nd_kernel(
        float* __restrict__ num, float* __restrict__ den) {
    int i = blockIdx.x * 256 + threadIdx.x;
    if (i < N_NODES * 4) { num[i] = 0.f; den[i] = 0.f; }
}

__global__ __launch_bounds__(256) void edge_acc2_kernel(
        const int* __restrict__ ei, const float* __restrict__ srcfeat,
        const float* __restrict__ dstfeat, float* __restrict__ num,
        float* __restrict__ den) {
    int e = blockIdx.x * 256 + threadIdx.x;
    if (e >= N_EDGES) return;
    int s = ei[e];
    int d = ei[N_EDGES + e];
    const float4* sp = (const float4*)(srcfeat + (size_t)s * 8);
    float4 as = sp[0];
    float4 g  = sp[1];
    float4 ad = *(const float4*)(dstfeat + (size_t)d * 4);
    float sc[4] = {as.x + ad.x, as.y + ad.y, as.z + ad.z, as.w + ad.w};
    float gg[4] = {g.x, g.y, g.z, g.w};
    float* np = num + (size_t)d * 4;
    float* dp = den + (size_t)d * 4;
#pragma unroll
    for (int h = 0; h < 4; ++h) {
        float v = sc[h] > 0.f ? sc[h] : NEG_SLOPE * sc[h];
        float ex = __expf(v);
        atomicAdd(dp + h, ex);
        atomicAdd(np + h, ex * gg[h]);
    }
}

__global__ __launch_bounds__(256) void finalize_kernel(
        const float* __restrict__ num, const float* __restrict__ den,
        const float* __restrict__ c0, float* __restrict__ out) {
    int n = blockIdx.x * 256 + threadIdx.x;
    if (n >= N_NODES) return;
    float4 nu = *(const float4*)(num + (size_t)n * 4);
    float4 de = *(const float4*)(den + (size_t)n * 4);
    out[n] = c0[0]
           + nu.x / (de.x + 1e-16f)
           + nu.y / (de.y + 1e-16f)
           + nu.z / (de.z + 1e-16f)
           + nu.w / (de.w + 1e-16f);
}

extern "C" void kernel_launch(void* const* d_in, const int* in_sizes, int n_in,
                              void* d_out, int out_size, void* d_ws, size_t ws_size,
                              hipStream_t stream) {
    const float* x       = (const float*)d_in[0];
    const int*   ei      = (const int*)d_in[1];
    const float* lin_w   = (const float*)d_in[2];
    const float* att_src = (const float*)d_in[3];
    const float* att_dst = (const float*)d_in[4];
    const float* bias    = (const float*)d_in[5];
    const float* fc_w    = (const float*)d_in[6];
    const float* fc_b    = (const float*)d_in[7];
    float* out = (float*)d_out;

    float* ws = (float*)d_ws;
    float* w_all   = ws;            // 3072 (+pad to 4096)
    float* c0      = ws + 3072;
    float* srcfeat = ws + 4096;     // 800000
    float* dstfeat = ws + 804096;   // 400000

    prep_kernel<<<4, 256, 0, stream>>>(lin_w, att_src, att_dst, fc_w, bias, fc_b, w_all, c0);
    // 8 nodes per wave, 32 per block
    node_kernel<<<(N_NODES + 31) / 32, 256, 0, stream>>>(x, w_all, srcfeat, dstfeat);

    // layout (words from ws base):
    // hist   @1204096  (400384)   -> 1604480
    // bcnt   @1604480  (1024 pad) -> 1605504
    // ocnt   @1605504  (64 pad)   -> 1605568
    // obuf   @1605568  (3200000)  -> 4805568
    // sorted @4805568  (2001920)  -> 6807488
    const size_t need_words = 6807488;
    if (ws_size >= need_words * 4) {
        int*  hist   = (int*)(ws + 1204096);
        int*  bcnt   = (int*)(ws + 1604480);
        int*  ocnt   = (int*)(ws + 1605504);
        int2* obuf   = (int2*)(ws + 1605568);
        int*  sorted = (int*)(ws + 4805568);

        hist2_kernel<<<B_SC, 256, 0, stream>>>(ei, hist);
        scanb_kernel<<<(W_BUCKETS + 3) / 4, 256, 0, stream>>>(hist, bcnt, ocnt);
        scatter2_kernel<<<B_SC, 256, 0, stream>>>(ei, hist, sorted, ocnt, obuf);
        agg4_kernel<<<W_BUCKETS, 256, 0, stream>>>(
            sorted, bcnt, srcfeat, dstfeat, c0, out, ocnt, obuf);
    } else {
        float* num = ws + 1204096;
        float* den = ws + 1604096;
        init_nd_kernel<<<(N_NODES * 4 + 255) / 256, 256, 0, stream>>>(num, den);
        edge_acc2_kernel<<<N_EDGES / 256, 256, 0, stream>>>(ei, srcfeat, dstfeat, num, den);
        finalize_kernel<<<(N_NODES + 255) / 256, 256, 0, stream>>>(num, den, c0, out);
    }
}

// Round 11
// 241.751 us; speedup vs baseline: 1.0439x; 1.0439x over previous
//
#include <hip/hip_runtime.h>
#include <math.h>

#define N_NODES 100000
#define N_EDGES 1600000
#define F_IN 256
#define HIDDEN 64
#define NEG_SLOPE 0.2f

#define BSHIFT 7               // bucket = dst>>7 (128 nodes/bucket)
#define BMASK 127
#define W_BUCKETS 782          // ceil(100000/128)
#define B_SC 512               // hist/scatter blocks (64*8 for scanb)
#define CHUNK 3125             // 512*3125 = 1600000 exactly
#define CAP 2560               // fixed slots per bucket (mean 2045, +11 sigma)

// ---- K0: fold att_src/att_dst/fc_w through lin_w ----
__global__ __launch_bounds__(256) void prep_kernel(
        const float* __restrict__ lin_w, const float* __restrict__ att_src,
        const float* __restrict__ att_dst, const float* __restrict__ fc_w,
        const float* __restrict__ bias, const float* __restrict__ fc_b,
        float* __restrict__ w_all, float* __restrict__ c0) {
    __shared__ float red[256];
    int h = blockIdx.x;   // 0..3
    int f = threadIdx.x;  // 0..255
    float a0 = 0.f, a1 = 0.f, a2 = 0.f;
    for (int c = 0; c < HIDDEN; ++c) {
        float lw = lin_w[(size_t)(h * HIDDEN + c) * F_IN + f];
        a0 += att_src[h * HIDDEN + c] * lw;
        a1 += att_dst[h * HIDDEN + c] * lw;
        a2 += fc_w[h * HIDDEN + c] * lw;
    }
    w_all[(0 + h) * F_IN + f] = a0;
    w_all[(4 + h) * F_IN + f] = a1;
    w_all[(8 + h) * F_IN + f] = a2;
    if (h == 0) {
        red[f] = bias[f] * fc_w[f];
        __syncthreads();
        for (int s = 128; s; s >>= 1) {
            if (f < s) red[f] += red[f + s];
            __syncthreads();
        }
        if (f == 0) c0[0] = red[0] + fc_b[0];
    }
}

// ---- K1: per-node 256x12 matvec; w_all staged in LDS (12 KB/block) ----
// 1 node per 16-lane group, VGPR ~64, 8 waves/SIMD. Empirically optimal:
// the 2-node variant (R9/R10) halved LDS issue but also halved wave count
// and raised VGPRs -> +11 us. Keep this shape.
__global__ __launch_bounds__(256) void node_kernel(
        const float* __restrict__ x, const float* __restrict__ w_all,
        float* __restrict__ srcfeat, float* __restrict__ dstfeat) {
    __shared__ float4 lw[768];  // 12 rows x 64 float4 = 12 KB
    int t = threadIdx.x;
    {
        const float4* wr = (const float4*)w_all;
        lw[t] = wr[t];
        lw[t + 256] = wr[t + 256];
        lw[t + 512] = wr[t + 512];
    }
    __syncthreads();
    int tid  = blockIdx.x * 256 + t;
    int wave = tid >> 6;
    int lane = t & 63;
    int sub  = lane >> 4;
    int l16  = lane & 15;
    int n = wave * 4 + sub;
    if (n >= N_NODES) return;
    const float4* xr = (const float4*)x + (size_t)n * 64;
    float p[12];
#pragma unroll
    for (int r = 0; r < 12; ++r) p[r] = 0.f;
#pragma unroll
    for (int k = 0; k < 4; ++k) {
        float4 xv = xr[l16 + 16 * k];
#pragma unroll
        for (int r = 0; r < 12; ++r) {
            float4 wv = lw[r * 64 + l16 + 16 * k];
            p[r] += xv.x * wv.x + xv.y * wv.y + xv.z * wv.z + xv.w * wv.w;
        }
    }
#pragma unroll
    for (int r = 0; r < 12; ++r) {
        float v = p[r];
        v += __shfl_xor(v, 1);
        v += __shfl_xor(v, 2);
        v += __shfl_xor(v, 4);
        v += __shfl_xor(v, 8);
        p[r] = v;
    }
    if (l16 == 0) {
        float4* sf = (float4*)(srcfeat + (size_t)n * 8);
        sf[0] = make_float4(p[0], p[1], p[2], p[3]);
        sf[1] = make_float4(p[8], p[9], p[10], p[11]);
        *(float4*)(dstfeat + (size_t)n * 4) = make_float4(p[4], p[5], p[6], p[7]);
    }
}

// =================== counting sort, static bucket regions ===================
// hist layout: hist[b * W_BUCKETS + k] (contiguous per block).

__global__ __launch_bounds__(256) void hist2_kernel(
        const int* __restrict__ ei, int* __restrict__ hist) {
    __shared__ int lcnt[W_BUCKETS];
    int t = threadIdx.x, b = blockIdx.x;
    for (int i = t; i < W_BUCKETS; i += 256) lcnt[i] = 0;
    __syncthreads();
    int base = b * CHUNK;
    int end = base + CHUNK; if (end > N_EDGES) end = N_EDGES;
    for (int e = base + t; e < end; e += 256)
        atomicAdd(&lcnt[ei[N_EDGES + e] >> BSHIFT], 1);
    __syncthreads();
    int* hb = hist + (size_t)b * W_BUCKETS;
    for (int i = t; i < W_BUCKETS; i += 256) hb[i] = lcnt[i];
}

// One wave per bucket: exclusive scan of the 512 per-block counts (8/lane),
// rebased to the bucket's static region k*CAP. Writes bucket total to bcnt.
__global__ __launch_bounds__(256) void scanb_kernel(
        int* __restrict__ hist, int* __restrict__ bcnt, int* __restrict__ ocnt) {
    if (blockIdx.x == 0 && threadIdx.x == 0) *ocnt = 0;
    int wv = (blockIdx.x * 256 + threadIdx.x) >> 6;  // bucket id
    int lane = threadIdx.x & 63;
    if (wv >= W_BUCKETS) return;
    int base = lane * 8;
    int v[8];
#pragma unroll
    for (int j = 0; j < 8; ++j)
        v[j] = hist[(size_t)(base + j) * W_BUCKETS + wv];
    int s[8];
    s[0] = v[0];
#pragma unroll
    for (int j = 1; j < 8; ++j) s[j] = s[j - 1] + v[j];
    int tot = s[7];
    int incl = tot;
#pragma unroll
    for (int off = 1; off < 64; off <<= 1) {
        int tmp = __shfl_up(incl, off);
        if (lane >= off) incl += tmp;
    }
    int excl = incl - tot;
    int b0 = wv * CAP;
#pragma unroll
    for (int j = 0; j < 8; ++j) {
        int pref = (j == 0) ? 0 : s[j - 1];
        hist[(size_t)(base + j) * W_BUCKETS + wv] = b0 + excl + pref;
    }
    if (lane == 63) bcnt[wv] = incl;
}

// place edges into static bucket regions: sorted[pos] = src | (dst&127)<<17
__global__ __launch_bounds__(256) void scatter2_kernel(
        const int* __restrict__ ei, const int* __restrict__ goff,
        int* __restrict__ sorted, int* __restrict__ ocnt,
        int2* __restrict__ obuf) {
    __shared__ int lbase[W_BUCKETS];
    int t = threadIdx.x, b = blockIdx.x;
    const int* gb = goff + (size_t)b * W_BUCKETS;
    for (int i = t; i < W_BUCKETS; i += 256) lbase[i] = gb[i];
    __syncthreads();
    int base = b * CHUNK;
    int end = base + CHUNK; if (end > N_EDGES) end = N_EDGES;
    for (int e = base + t; e < end; e += 256) {
        int s = ei[e];
        int d = ei[N_EDGES + e];
        int k = d >> BSHIFT;
        int pos = atomicAdd(&lbase[k], 1);
        if (pos < (k + 1) * CAP) {
            sorted[pos] = s | ((d & BMASK) << 17);
        } else {
            int oi = atomicAdd(ocnt, 1);
            obuf[oi] = make_int2(s, d);
        }
    }
}

// ---- agg4: per-bucket in-LDS fine sort + atomic-free per-node aggregation ----
__global__ __launch_bounds__(256) void agg4_kernel(
        const int* __restrict__ sorted, const int* __restrict__ bcnt,
        const float* __restrict__ srcfeat, const float* __restrict__ dstfeat,
        const float* __restrict__ c0, float* __restrict__ out,
        const int* __restrict__ ocnt, const int2* __restrict__ obuf) {
    __shared__ int eds[CAP];
    __shared__ int srt[CAP];
    __shared__ int cnt[128];   // hist, then cursor
    __shared__ int bnd[129];   // exclusive bounds
    __shared__ int s_oc;
    int t = threadIdx.x, k = blockIdx.x;
    if (t == 0) s_oc = *ocnt;
    int begin = k * CAP;
    int len = bcnt[k];
    int lcap = len < CAP ? len : CAP;
    if (t < 128) cnt[t] = 0;
    __syncthreads();
    for (int i = t; i < lcap; i += 256) {
        int p = sorted[begin + i];
        eds[i] = p;
        atomicAdd(&cnt[p >> 17], 1);
    }
    __syncthreads();
    if (t < 128) bnd[t + 1] = cnt[t];
    __syncthreads();
    for (int off = 1; off < 128; off <<= 1) {
        int v = 0;
        if (t < 128 && t >= off) v = bnd[t + 1 - off];
        __syncthreads();
        if (t < 128) bnd[t + 1] += v;
        __syncthreads();
    }
    if (t == 0) bnd[0] = 0;
    if (t < 128) cnt[t] = (t == 0) ? 0 : bnd[t];
    __syncthreads();
    for (int i = t; i < lcap; i += 256) {
        int p = eds[i];
        int pos = atomicAdd(&cnt[p >> 17], 1);
        srt[pos] = p & 0x1FFFF;
    }
    __syncthreads();
    if (t < 128) {
        int n0 = k * 128 + t;
        if (n0 < N_NODES) {
            float4 ad = *(const float4*)(dstfeat + (size_t)n0 * 4);
            float de0 = 0.f, de1 = 0.f, de2 = 0.f, de3 = 0.f;
            float nu0 = 0.f, nu1 = 0.f, nu2 = 0.f, nu3 = 0.f;
            int b0 = bnd[t], e0 = bnd[t + 1];
            for (int i = b0; i < e0; ++i) {
                int s = srt[i];
                const float4* sp = (const float4*)(srcfeat + (size_t)s * 8);
                float4 as = sp[0];
                float4 g  = sp[1];
                float s0 = as.x + ad.x, s1 = as.y + ad.y;
                float s2 = as.z + ad.z, s3 = as.w + ad.w;
                float x0 = __expf(s0 > 0.f ? s0 : NEG_SLOPE * s0);
                float x1 = __expf(s1 > 0.f ? s1 : NEG_SLOPE * s1);
                float x2 = __expf(s2 > 0.f ? s2 : NEG_SLOPE * s2);
                float x3 = __expf(s3 > 0.f ? s3 : NEG_SLOPE * s3);
                de0 += x0; de1 += x1; de2 += x2; de3 += x3;
                nu0 += x0 * g.x; nu1 += x1 * g.y; nu2 += x2 * g.z; nu3 += x3 * g.w;
            }
            // overflow edges (empty in practice)
            for (int i = 0; i < s_oc; ++i) {
                int2 e = obuf[i];
                if ((e.y >> BSHIFT) == k && (e.y & BMASK) == t) {
                    const float4* sp = (const float4*)(srcfeat + (size_t)e.x * 8);
                    float4 as = sp[0];
                    float4 g  = sp[1];
                    float s0 = as.x + ad.x, s1 = as.y + ad.y;
                    float s2 = as.z + ad.z, s3 = as.w + ad.w;
                    float x0 = __expf(s0 > 0.f ? s0 : NEG_SLOPE * s0);
                    float x1 = __expf(s1 > 0.f ? s1 : NEG_SLOPE * s1);
                    float x2 = __expf(s2 > 0.f ? s2 : NEG_SLOPE * s2);
                    float x3 = __expf(s3 > 0.f ? s3 : NEG_SLOPE * s3);
                    de0 += x0; de1 += x1; de2 += x2; de3 += x3;
                    nu0 += x0 * g.x; nu1 += x1 * g.y; nu2 += x2 * g.z; nu3 += x3 * g.w;
                }
            }
            float y = c0[0]
                    + nu0 / (de0 + 1e-16f)
                    + nu1 / (de1 + 1e-16f)
                    + nu2 / (de2 + 1e-16f)
                    + nu3 / (de3 + 1e-16f);
            out[n0] = y;
        }
    }
}

// =================== fallback atomic path (tiny ws) ===================

__global__ __launch_bounds__(256) void init_nd_kernel(
        float* __restrict__ num, float* __restrict__ den) {
    int i = blockIdx.x * 256 + threadIdx.x;
    if (i < N_NODES * 4) { num[i] = 0.f; den[i] = 0.f; }
}

__global__ __launch_bounds__(256) void edge_acc2_kernel(
        const int* __restrict__ ei, const float* __restrict__ srcfeat,
        const float* __restrict__ dstfeat, float* __restrict__ num,
        float* __restrict__ den) {
    int e = blockIdx.x * 256 + threadIdx.x;
    if (e >= N_EDGES) return;
    int s = ei[e];
    int d = ei[N_EDGES + e];
    const float4* sp = (const float4*)(srcfeat + (size_t)s * 8);
    float4 as = sp[0];
    float4 g  = sp[1];
    float4 ad = *(const float4*)(dstfeat + (size_t)d * 4);
    float sc[4] = {as.x + ad.x, as.y + ad.y, as.z + ad.z, as.w + ad.w};
    float gg[4] = {g.x, g.y, g.z, g.w};
    float* np = num + (size_t)d * 4;
    float* dp = den + (size_t)d * 4;
#pragma unroll
    for (int h = 0; h < 4; ++h) {
        float v = sc[h] > 0.f ? sc[h] : NEG_SLOPE * sc[h];
        float ex = __expf(v);
        atomicAdd(dp + h, ex);
        atomicAdd(np + h, ex * gg[h]);
    }
}

__global__ __launch_bounds__(256) void finalize_kernel(
        const float* __restrict__ num, const float* __restrict__ den,
        const float* __restrict__ c0, float* __restrict__ out) {
    int n = blockIdx.x * 256 + threadIdx.x;
    if (n >= N_NODES) return;
    float4 nu = *(const float4*)(num + (size_t)n * 4);
    float4 de = *(const float4*)(den + (size_t)n * 4);
    out[n] = c0[0]
           + nu.x / (de.x + 1e-16f)
           + nu.y / (de.y + 1e-16f)
           + nu.z / (de.z + 1e-16f)
           + nu.w / (de.w + 1e-16f);
}

extern "C" void kernel_launch(void* const* d_in, const int* in_sizes, int n_in,
                              void* d_out, int out_size, void* d_ws, size_t ws_size,
                              hipStream_t stream) {
    const float* x       = (const float*)d_in[0];
    const int*   ei      = (const int*)d_in[1];
    const float* lin_w   = (const float*)d_in[2];
    const float* att_src = (const float*)d_in[3];
    const float* att_dst = (const float*)d_in[4];
    const float* bias    = (const float*)d_in[5];
    const float* fc_w    = (const float*)d_in[6];
    const float* fc_b    = (const float*)d_in[7];
    float* out = (float*)d_out;

    float* ws = (float*)d_ws;
    float* w_all   = ws;            // 3072 (+pad to 4096)
    float* c0      = ws + 3072;
    float* srcfeat = ws + 4096;     // 800000
    float* dstfeat = ws + 804096;   // 400000

    prep_kernel<<<4, 256, 0, stream>>>(lin_w, att_src, att_dst, fc_w, bias, fc_b, w_all, c0);
    node_kernel<<<(N_NODES + 15) / 16, 256, 0, stream>>>(x, w_all, srcfeat, dstfeat);

    // layout (words from ws base):
    // hist   @1204096  (400384)   -> 1604480
    // bcnt   @1604480  (1024 pad) -> 1605504
    // ocnt   @1605504  (64 pad)   -> 1605568
    // obuf   @1605568  (3200000)  -> 4805568
    // sorted @4805568  (2001920)  -> 6807488
    const size_t need_words = 6807488;
    if (ws_size >= need_words * 4) {
        int*  hist   = (int*)(ws + 1204096);
        int*  bcnt   = (int*)(ws + 1604480);
        int*  ocnt   = (int*)(ws + 1605504);
        int2* obuf   = (int2*)(ws + 1605568);
        int*  sorted = (int*)(ws + 4805568);

        hist2_kernel<<<B_SC, 256, 0, stream>>>(ei, hist);
        scanb_kernel<<<(W_BUCKETS + 3) / 4, 256, 0, stream>>>(hist, bcnt, ocnt);
        scatter2_kernel<<<B_SC, 256, 0, stream>>>(ei, hist, sorted, ocnt, obuf);
        agg4_kernel<<<W_BUCKETS, 256, 0, stream>>>(
            sorted, bcnt, srcfeat, dstfeat, c0, out, ocnt, obuf);
    } else {
        float* num = ws + 1204096;
        float* den = ws + 1604096;
        init_nd_kernel<<<(N_NODES * 4 + 255) / 256, 256, 0, stream>>>(num, den);
        edge_acc2_kernel<<<N_EDGES / 256, 256, 0, stream>>>(ei, srcfeat, dstfeat, num, den);
        finalize_kernel<<<(N_NODES + 255) / 256, 256, 0, stream>>>(num, den, c0, out);
    }
}